// Round 1
// 853.035 us; speedup vs baseline: 1.0808x; 1.0808x over previous
//
#include <hip/hip_runtime.h>

// Attractor net (all I/O float32): c = x@Win^T + bin; a=0; 15x: a = tanh(a@Ws^T + b + c),
// Ws = 0.5(W+W^T); y = a@Wout^T + bout.  x (65536,256), N=512, C=256.
//
// Round-3 restructure: 64 samples/block, 512 threads (8 waves), grid 1024.
//  - Previous round was latency-bound at 2 waves/SIMD (1 block/CU, 133KB LDS, ~256 regs):
//    MfmaUtil == Occupancy == 25%. Halving samples/block halves LDS (66,560B) and the
//    register footprint (acc 64, c_pk 32) -> 2 blocks/CU, 4 waves/SIMD.
//  - Wave w owns feature rows [w*64, w*64+64) for all 64 samples; each Ws A-fragment
//    loaded by exactly one wave, feeds 2 MFMAs (2 sample-tiles). Ws L2 traffic doubles
//    vs round-2 (7.3GB total, ~213us chip floor) but overlaps with compute.
//  - a lives in LDS bf16 (64 rows x 512 feat, XOR-swizzled 8B units), 64 KB.
//  - c (+ biases) persists bf16-packed in 32 VGPRs/lane; acc (64 regs) re-inits from it.

using bf16x8 = __attribute__((ext_vector_type(8))) __bf16;
using f32x16 = __attribute__((ext_vector_type(16))) float;

union BQ {
  unsigned long long q[2];
  uint4 u4;
};

// round-to-nearest bf16 pack of two floats into one u32 (lo = a, hi = b)
__device__ __forceinline__ unsigned int pack2bf(float a, float b) {
  unsigned int ua = __builtin_bit_cast(unsigned int, a);
  unsigned int ub = __builtin_bit_cast(unsigned int, b);
  return ((ua + 0x8000u) >> 16) | ((ub + 0x8000u) & 0xffff0000u);
}

__device__ __forceinline__ unsigned short f2bf(float v) {
  unsigned int u = __builtin_bit_cast(unsigned int, v);
  return (unsigned short)((u + 0x7fffu + ((u >> 16) & 1u)) >> 16);  // RNE
}

__device__ __forceinline__ float fast_tanh(float x) {
  // tanh(x) = 1 - 2/(e^{2x}+1);  e^{2x} = 2^{x*2*log2(e)}
  float e = __builtin_amdgcn_exp2f(x * 2.885390082f);
  float r = __builtin_amdgcn_rcpf(e + 1.0f);
  return __builtin_fmaf(-2.0f, r, 1.0f);
}

__device__ __forceinline__ f32x16 mfma32(uint4 a, uint4 b, f32x16 c) {
  return __builtin_amdgcn_mfma_f32_32x32x16_bf16(
      __builtin_bit_cast(bf16x8, a), __builtin_bit_cast(bf16x8, b), c, 0, 0, 0);
}

// ---------------- prep ----------------
// Task 1: WsP = bf16 A-fragment layout of 0.5*(W + W^T).
//   Fragment block (s, mtG) is 1KB: lane L holds Ws[m = mtG*32 + (L&31)][k = s*16 + (L>>5)*8 + j]
//   at element offset ((s*16+mtG)*64 + L)*8 + j.
// Task 2: row-major f32->bf16 copies of Win (131072 elems) and Wout (131072 elems).
__global__ void prep(const float* __restrict__ W,
                     const float* __restrict__ Win,
                     const float* __restrict__ Wout,
                     unsigned short* __restrict__ WsPo,
                     unsigned short* __restrict__ WinBf,
                     unsigned short* __restrict__ WoutBf) {
  int t = blockIdx.x * 256 + threadIdx.x;   // 0 .. 262143
  int e   = t & 511;
  int bid = t >> 9;
  int s  = bid >> 4;
  int mt = bid & 15;
  int L = e >> 3, j = e & 7;
  int m = mt * 32 + (L & 31);
  int k = s * 16 + (L >> 5) * 8 + j;
  WsPo[t] = f2bf(0.5f * (W[m * 512 + k] + W[k * 512 + m]));
  if (t < 131072) WinBf[t] = f2bf(Win[t]);
  else            WoutBf[t - 131072] = f2bf(Wout[t - 131072]);
}

// ---------------- main fused kernel ----------------
__global__ __launch_bounds__(512, 4) void attractor_kernel(
    const float* __restrict__ x,              // 65536 x 256 f32
    const unsigned short* __restrict__ WinBf, // 512 x 256 bf16
    const float* __restrict__ binf,           // 512 f32
    const float* __restrict__ brecf,          // 512 f32
    const unsigned short* __restrict__ WoutBf,// 256 x 512 bf16
    const float* __restrict__ boutf,          // 256 f32
    const uint4* __restrict__ WsP,            // packed 512 KB bf16
    float* __restrict__ y)                    // 65536 x 256 f32
{
  __shared__ uint4 smem4[4160];               // 66,560 B (a: 64KB; y-stage: 64x65 uint4)
  unsigned long long* a_sh = (unsigned long long*)smem4;

  const int tid  = threadIdx.x;
  const int lane = tid & 63;
  const int w    = tid >> 6;    // wave 0..7
  const int il   = lane & 31;   // row-within-32-tile
  const int g    = lane >> 5;   // k-group (0/1)
  const int m15  = il & 15;     // LDS swizzle mask
  const int blk  = blockIdx.x;

  const float4* __restrict__ xf4  = (const float4*)x;       // row = 64 float4
  const uint4* __restrict__ Win4  = (const uint4*)WinBf;    // row = 32 uint4
  const uint4* __restrict__ Wout4 = (const uint4*)WoutBf;   // row = 64 uint4
  uint4* __restrict__ y4 = (uint4*)y;                       // row = 64 uint4

  f32x16 acc[2][2];             // [mt][nt], 64 VGPRs
  unsigned int c_pk[2][2][8];   // 32 VGPRs

  // ---------- Phase 1: in_proj  c^T = Win @ x^T  (K = 256 -> 16 steps) ----------
  #pragma unroll
  for (int mt = 0; mt < 2; ++mt)
    #pragma unroll
    for (int nt = 0; nt < 2; ++nt)
      #pragma unroll
      for (int r = 0; r < 16; ++r) acc[mt][nt][r] = 0.0f;

  #pragma unroll 2
  for (int s = 0; s < 16; ++s) {
    uint4 A[2], B[2];
    #pragma unroll
    for (int mt = 0; mt < 2; ++mt) {
      int m = w * 64 + mt * 32 + il;           // feature row of Win
      A[mt] = Win4[m * 32 + 2 * s + g];
    }
    #pragma unroll
    for (int nt = 0; nt < 2; ++nt) {
      int i = blk * 64 + nt * 32 + il;         // sample row of x
      float4 f0 = xf4[i * 64 + 4 * s + 2 * g + 0];
      float4 f1 = xf4[i * 64 + 4 * s + 2 * g + 1];
      B[nt].x = pack2bf(f0.x, f0.y);
      B[nt].y = pack2bf(f0.z, f0.w);
      B[nt].z = pack2bf(f1.x, f1.y);
      B[nt].w = pack2bf(f1.z, f1.w);
    }
    #pragma unroll
    for (int mt = 0; mt < 2; ++mt)
      #pragma unroll
      for (int nt = 0; nt < 2; ++nt)
        acc[mt][nt] = mfma32(A[mt], B[nt], acc[mt][nt]);
  }

  // epilogue: fold biases into c, stash packed c
  #pragma unroll
  for (int mt = 0; mt < 2; ++mt) {
    #pragma unroll
    for (int p = 0; p < 4; ++p) {
      const int n0 = w * 64 + mt * 32 + 8 * p + 4 * g;
      float b0 = binf[n0 + 0] + brecf[n0 + 0];
      float b1 = binf[n0 + 1] + brecf[n0 + 1];
      float b2 = binf[n0 + 2] + brecf[n0 + 2];
      float b3 = binf[n0 + 3] + brecf[n0 + 3];
      #pragma unroll
      for (int nt = 0; nt < 2; ++nt) {
        acc[mt][nt][4 * p + 0] += b0;
        acc[mt][nt][4 * p + 1] += b1;
        acc[mt][nt][4 * p + 2] += b2;
        acc[mt][nt][4 * p + 3] += b3;
        c_pk[mt][nt][2 * p + 0] = pack2bf(acc[mt][nt][4 * p + 0], acc[mt][nt][4 * p + 1]);
        c_pk[mt][nt][2 * p + 1] = pack2bf(acc[mt][nt][4 * p + 2], acc[mt][nt][4 * p + 3]);
      }
    }
  }

  // tanh + swizzled bf16 store of a into LDS
  auto tanhStore = [&]() {
    #pragma unroll
    for (int mt = 0; mt < 2; ++mt)
      #pragma unroll
      for (int nt = 0; nt < 2; ++nt) {
        const int irow = nt * 32 + il;
        #pragma unroll
        for (int p = 0; p < 4; ++p) {
          float t0 = fast_tanh(acc[mt][nt][4 * p + 0]);
          float t1 = fast_tanh(acc[mt][nt][4 * p + 1]);
          float t2 = fast_tanh(acc[mt][nt][4 * p + 2]);
          float t3 = fast_tanh(acc[mt][nt][4 * p + 3]);
          unsigned long long qv =
              (unsigned long long)pack2bf(t0, t1) |
              ((unsigned long long)pack2bf(t2, t3) << 32);
          const int u = w * 16 + mt * 8 + 2 * p + g;   // 8B unit within 128-unit row
          a_sh[irow * 128 + (u ^ m15)] = qv;
        }
      }
  };
  tanhStore();
  __syncthreads();

  // ---------- Phase 2: 14 iterations  z^T = Ws @ a^T  (K = 512 -> 32 steps) ----------
  const uint4* pA = WsP + (w * 2) * 64 + lane;   // + s*1024 + mt*64

  #pragma unroll 1
  for (int it = 0; it < 14; ++it) {
    // acc <- c (bf16-unpacked; biases already folded in)
    #pragma unroll
    for (int mt = 0; mt < 2; ++mt)
      #pragma unroll
      for (int nt = 0; nt < 2; ++nt)
        #pragma unroll
        for (int p = 0; p < 4; ++p) {
          unsigned int u01 = c_pk[mt][nt][2 * p + 0];
          unsigned int u23 = c_pk[mt][nt][2 * p + 1];
          acc[mt][nt][4 * p + 0] = __builtin_bit_cast(float, u01 << 16);
          acc[mt][nt][4 * p + 1] = __builtin_bit_cast(float, u01 & 0xffff0000u);
          acc[mt][nt][4 * p + 2] = __builtin_bit_cast(float, u23 << 16);
          acc[mt][nt][4 * p + 3] = __builtin_bit_cast(float, u23 & 0xffff0000u);
        }

    uint4 Ab[2][2];   // [slot][mt] double buffer
    #pragma unroll
    for (int mt = 0; mt < 2; ++mt) Ab[0][mt] = pA[mt * 64];

    #pragma unroll 2
    for (int s = 0; s < 32; ++s) {
      if (s + 1 < 32) {
        #pragma unroll
        for (int mt = 0; mt < 2; ++mt)
          Ab[(s + 1) & 1][mt] = pA[(s + 1) * 1024 + mt * 64];
      }
      const int u0 = 4 * s + 2 * g;
      BQ B[2];
      #pragma unroll
      for (int nt = 0; nt < 2; ++nt) {
        const int base = (nt * 32 + il) * 128;
        B[nt].q[0] = a_sh[base + ((u0 + 0) ^ m15)];
        B[nt].q[1] = a_sh[base + ((u0 + 1) ^ m15)];
      }
      #pragma unroll
      for (int mt = 0; mt < 2; ++mt)
        #pragma unroll
        for (int nt = 0; nt < 2; ++nt)
          acc[mt][nt] = mfma32(Ab[s & 1][mt], B[nt].u4, acc[mt][nt]);
    }
    __syncthreads();   // all reads of old a done
    tanhStore();       // overwrite a in place
    __syncthreads();   // new a visible to all waves
  }

  // ---------- Phase 3: out_proj  y^T = Wout @ a^T (wave w -> channels [w*32, w*32+32)) ----------
  f32x16 o[2];
  #pragma unroll
  for (int nt = 0; nt < 2; ++nt)
    #pragma unroll
    for (int r = 0; r < 16; ++r) o[nt][r] = 0.0f;

  #pragma unroll 2
  for (int s = 0; s < 32; ++s) {
    const int m = w * 32 + il;                  // output-channel row of Wout
    uint4 A = Wout4[m * 64 + 2 * s + g];
    const int u0 = 4 * s + 2 * g;
    BQ B[2];
    #pragma unroll
    for (int nt = 0; nt < 2; ++nt) {
      const int base = (nt * 32 + il) * 128;
      B[nt].q[0] = a_sh[base + ((u0 + 0) ^ m15)];
      B[nt].q[1] = a_sh[base + ((u0 + 1) ^ m15)];
    }
    #pragma unroll
    for (int nt = 0; nt < 2; ++nt)
      o[nt] = mfma32(A, B[nt].u4, o[nt]);
  }
  __syncthreads();   // done reading a; reuse LDS as y staging

  // epilogue: +bout, stage f32 rows into LDS (stride-65 uint4 rows)
  uint4* yst4 = smem4;
  #pragma unroll
  for (int p = 0; p < 4; ++p) {
    const int c0 = w * 32 + 8 * p + 4 * g;
    float b0 = boutf[c0 + 0];
    float b1 = boutf[c0 + 1];
    float b2 = boutf[c0 + 2];
    float b3 = boutf[c0 + 3];
    #pragma unroll
    for (int nt = 0; nt < 2; ++nt) {
      const int irow = nt * 32 + il;
      float4 r;
      r.x = o[nt][4 * p + 0] + b0;
      r.y = o[nt][4 * p + 1] + b1;
      r.z = o[nt][4 * p + 2] + b2;
      r.w = o[nt][4 * p + 3] + b3;
      yst4[irow * 65 + (c0 >> 2)] = __builtin_bit_cast(uint4, r);
    }
  }
  __syncthreads();

  // coalesced f32 store: 4096 uint4 per block, 8 passes x 512 threads
  #pragma unroll
  for (int p = 0; p < 8; ++p) {
    int idx = p * 512 + tid;
    int row = idx >> 6;
    int col = idx & 63;
    y4[(blk * 64 + row) * 64 + col] = yst4[row * 65 + col];
  }
}

extern "C" void kernel_launch(void* const* d_in, const int* in_sizes, int n_in,
                              void* d_out, int out_size, void* d_ws, size_t ws_size,
                              hipStream_t stream) {
  const float* x    = (const float*)d_in[0];
  const float* Win  = (const float*)d_in[1];
  const float* bin  = (const float*)d_in[2];
  const float* W    = (const float*)d_in[3];
  const float* brec = (const float*)d_in[4];
  const float* Wout = (const float*)d_in[5];
  const float* bout = (const float*)d_in[6];

  unsigned short* wsu    = (unsigned short*)d_ws;
  unsigned short* WsP    = wsu;            // 262144 bf16 = 512 KB
  unsigned short* WinBf  = wsu + 262144;   // 131072 bf16 = 256 KB
  unsigned short* WoutBf = wsu + 393216;   // 131072 bf16 = 256 KB

  prep<<<1024, 256, 0, stream>>>(W, Win, Wout, WsP, WinBf, WoutBf);
  attractor_kernel<<<1024, 512, 0, stream>>>(x, WinBf, bin, brec, WoutBf, bout,
                                             (const uint4*)WsP, (float*)d_out);
}

// Round 2
// 772.018 us; speedup vs baseline: 1.1942x; 1.1049x over previous
//
#include <hip/hip_runtime.h>

// Attractor net (all I/O float32): c = x@Win^T + bin; a=0; 15x: a = tanh(a@Ws^T + b + c),
// Ws = 0.5(W+W^T); y = a@Wout^T + bout.  x (65536,256), N=512, C=256.
//
// Round-4: latency/convoy attack on the round-3 structure (64 samples/block, 8 waves,
// 2 blocks/CU, 4 waves/SIMD).
//  - Continuous A-prefetch: se=(s+4w)&31 staggered sweep; the s=31 prefetch wraps to the
//    NEXT iteration's first fragment, so the Ws load chain crosses the tanh+barriers with
//    ~1500cy of cover (was: cold restart every iteration, 1-step cover vs 200-900cy L2/HBM).
//  - Per-wave s-stagger de-convoys the 8 waves' L2 traffic (8 different 16KB stripes live).
//  - a_sh re-swizzled on 16B units, XOR key = il (5 bits): B fragment = ONE ds_read_b128
//    (was 2x ds_read_b64) -> LDS read instr count halves; writes spread over 512B (no
//    bank conflicts by construction).
//  - c (+ biases) persists bf16-packed in 32 VGPRs/lane; acc (64 regs) re-inits from it.

using bf16x8 = __attribute__((ext_vector_type(8))) __bf16;
using f32x16 = __attribute__((ext_vector_type(16))) float;

// round-to-nearest bf16 pack of two floats into one u32 (lo = a, hi = b)
__device__ __forceinline__ unsigned int pack2bf(float a, float b) {
  unsigned int ua = __builtin_bit_cast(unsigned int, a);
  unsigned int ub = __builtin_bit_cast(unsigned int, b);
  return ((ua + 0x8000u) >> 16) | ((ub + 0x8000u) & 0xffff0000u);
}

__device__ __forceinline__ unsigned short f2bf(float v) {
  unsigned int u = __builtin_bit_cast(unsigned int, v);
  return (unsigned short)((u + 0x7fffu + ((u >> 16) & 1u)) >> 16);  // RNE
}

__device__ __forceinline__ float fast_tanh(float x) {
  // tanh(x) = 1 - 2/(e^{2x}+1);  e^{2x} = 2^{x*2*log2(e)}
  float e = __builtin_amdgcn_exp2f(x * 2.885390082f);
  float r = __builtin_amdgcn_rcpf(e + 1.0f);
  return __builtin_fmaf(-2.0f, r, 1.0f);
}

__device__ __forceinline__ f32x16 mfma32(uint4 a, uint4 b, f32x16 c) {
  return __builtin_amdgcn_mfma_f32_32x32x16_bf16(
      __builtin_bit_cast(bf16x8, a), __builtin_bit_cast(bf16x8, b), c, 0, 0, 0);
}

// ---------------- prep ----------------
// Task 1: WsP = bf16 A-fragment layout of 0.5*(W + W^T).
//   Fragment block (s, mtG) is 1KB: lane L holds Ws[m = mtG*32 + (L&31)][k = s*16 + (L>>5)*8 + j]
//   at element offset ((s*16+mtG)*64 + L)*8 + j.
// Task 2: row-major f32->bf16 copies of Win (131072 elems) and Wout (131072 elems).
__global__ void prep(const float* __restrict__ W,
                     const float* __restrict__ Win,
                     const float* __restrict__ Wout,
                     unsigned short* __restrict__ WsPo,
                     unsigned short* __restrict__ WinBf,
                     unsigned short* __restrict__ WoutBf) {
  int t = blockIdx.x * 256 + threadIdx.x;   // 0 .. 262143
  int e   = t & 511;
  int bid = t >> 9;
  int s  = bid >> 4;
  int mt = bid & 15;
  int L = e >> 3, j = e & 7;
  int m = mt * 32 + (L & 31);
  int k = s * 16 + (L >> 5) * 8 + j;
  WsPo[t] = f2bf(0.5f * (W[m * 512 + k] + W[k * 512 + m]));
  if (t < 131072) WinBf[t] = f2bf(Win[t]);
  else            WoutBf[t - 131072] = f2bf(Wout[t - 131072]);
}

// ---------------- main fused kernel ----------------
__global__ __launch_bounds__(512, 4) void attractor_kernel(
    const float* __restrict__ x,              // 65536 x 256 f32
    const unsigned short* __restrict__ WinBf, // 512 x 256 bf16
    const float* __restrict__ binf,           // 512 f32
    const float* __restrict__ brecf,          // 512 f32
    const unsigned short* __restrict__ WoutBf,// 256 x 512 bf16
    const float* __restrict__ boutf,          // 256 f32
    const uint4* __restrict__ WsP,            // packed 512 KB bf16
    float* __restrict__ y)                    // 65536 x 256 f32
{
  __shared__ uint4 smem4[4160];               // 66,560 B (a: 64KB; y-stage: 64x65 uint4)
  unsigned long long* a_sh = (unsigned long long*)smem4;

  const int tid  = threadIdx.x;
  const int lane = tid & 63;
  const int w    = tid >> 6;    // wave 0..7
  const int il   = lane & 31;   // row-within-32-tile; also the 5-bit LDS swizzle key
  const int g    = lane >> 5;   // k-group (0/1)
  const int sw   = w * 4;       // per-wave K-sweep stagger
  const int blk  = blockIdx.x;

  const float4* __restrict__ xf4  = (const float4*)x;       // row = 64 float4
  const uint4* __restrict__ Win4  = (const uint4*)WinBf;    // row = 32 uint4
  const uint4* __restrict__ Wout4 = (const uint4*)WoutBf;   // row = 64 uint4
  uint4* __restrict__ y4 = (uint4*)y;                       // row = 64 uint4

  f32x16 acc[2][2];             // [mt][nt], 64 VGPRs
  unsigned int c_pk[2][2][8];   // 32 VGPRs

  // ---------- Phase 1: in_proj  c^T = Win @ x^T  (K = 256 -> 16 steps) ----------
  #pragma unroll
  for (int mt = 0; mt < 2; ++mt)
    #pragma unroll
    for (int nt = 0; nt < 2; ++nt)
      #pragma unroll
      for (int r = 0; r < 16; ++r) acc[mt][nt][r] = 0.0f;

  #pragma unroll 2
  for (int s = 0; s < 16; ++s) {
    uint4 A[2], B[2];
    #pragma unroll
    for (int mt = 0; mt < 2; ++mt) {
      int m = w * 64 + mt * 32 + il;           // feature row of Win
      A[mt] = Win4[m * 32 + 2 * s + g];
    }
    #pragma unroll
    for (int nt = 0; nt < 2; ++nt) {
      int i = blk * 64 + nt * 32 + il;         // sample row of x
      float4 f0 = xf4[i * 64 + 4 * s + 2 * g + 0];
      float4 f1 = xf4[i * 64 + 4 * s + 2 * g + 1];
      B[nt].x = pack2bf(f0.x, f0.y);
      B[nt].y = pack2bf(f0.z, f0.w);
      B[nt].z = pack2bf(f1.x, f1.y);
      B[nt].w = pack2bf(f1.z, f1.w);
    }
    #pragma unroll
    for (int mt = 0; mt < 2; ++mt)
      #pragma unroll
      for (int nt = 0; nt < 2; ++nt)
        acc[mt][nt] = mfma32(A[mt], B[nt], acc[mt][nt]);
  }

  // epilogue: fold biases into c, stash packed c
  #pragma unroll
  for (int mt = 0; mt < 2; ++mt) {
    #pragma unroll
    for (int p = 0; p < 4; ++p) {
      const int n0 = w * 64 + mt * 32 + 8 * p + 4 * g;
      float b0 = binf[n0 + 0] + brecf[n0 + 0];
      float b1 = binf[n0 + 1] + brecf[n0 + 1];
      float b2 = binf[n0 + 2] + brecf[n0 + 2];
      float b3 = binf[n0 + 3] + brecf[n0 + 3];
      #pragma unroll
      for (int nt = 0; nt < 2; ++nt) {
        acc[mt][nt][4 * p + 0] += b0;
        acc[mt][nt][4 * p + 1] += b1;
        acc[mt][nt][4 * p + 2] += b2;
        acc[mt][nt][4 * p + 3] += b3;
        c_pk[mt][nt][2 * p + 0] = pack2bf(acc[mt][nt][4 * p + 0], acc[mt][nt][4 * p + 1]);
        c_pk[mt][nt][2 * p + 1] = pack2bf(acc[mt][nt][4 * p + 2], acc[mt][nt][4 * p + 3]);
      }
    }
  }

  // tanh + swizzled bf16 store of a into LDS.
  // 16B-unit index v_w = w*8 + mt*4 + p (wave-constant), half g; swizzle: pos = v_w ^ il.
  // 64 lanes hit 32 positions x 2 halves = 512B of distinct 8B slots -> conflict-free.
  auto tanhStore = [&]() {
    #pragma unroll
    for (int mt = 0; mt < 2; ++mt)
      #pragma unroll
      for (int nt = 0; nt < 2; ++nt) {
        const int irow = nt * 32 + il;
        #pragma unroll
        for (int p = 0; p < 4; ++p) {
          float t0 = fast_tanh(acc[mt][nt][4 * p + 0]);
          float t1 = fast_tanh(acc[mt][nt][4 * p + 1]);
          float t2 = fast_tanh(acc[mt][nt][4 * p + 2]);
          float t3 = fast_tanh(acc[mt][nt][4 * p + 3]);
          unsigned long long qv =
              (unsigned long long)pack2bf(t0, t1) |
              ((unsigned long long)pack2bf(t2, t3) << 32);
          const int v_w = w * 8 + mt * 4 + p;          // 16B unit within 64-unit row
          a_sh[irow * 128 + (((v_w ^ il) << 1) | g)] = qv;
        }
      }
  };
  tanhStore();

  // cross-barrier prefetch of the first Ws fragments (it=0, se=sw)
  const uint4* pA = WsP + (w * 2) * 64 + lane;   // + se*1024 + mt*64
  uint4 Ab[2][2];   // [slot][mt]
  #pragma unroll
  for (int mt = 0; mt < 2; ++mt) Ab[0][mt] = pA[sw * 1024 + mt * 64];

  __syncthreads();

  // ---------- Phase 2: 14 iterations  z^T = Ws @ a^T  (K = 512 -> 32 steps) ----------
  #pragma unroll 1
  for (int it = 0; it < 14; ++it) {
    // acc <- c (bf16-unpacked; biases already folded in)
    #pragma unroll
    for (int mt = 0; mt < 2; ++mt)
      #pragma unroll
      for (int nt = 0; nt < 2; ++nt)
        #pragma unroll
        for (int p = 0; p < 4; ++p) {
          unsigned int u01 = c_pk[mt][nt][2 * p + 0];
          unsigned int u23 = c_pk[mt][nt][2 * p + 1];
          acc[mt][nt][4 * p + 0] = __builtin_bit_cast(float, u01 << 16);
          acc[mt][nt][4 * p + 1] = __builtin_bit_cast(float, u01 & 0xffff0000u);
          acc[mt][nt][4 * p + 2] = __builtin_bit_cast(float, u23 << 16);
          acc[mt][nt][4 * p + 3] = __builtin_bit_cast(float, u23 & 0xffff0000u);
        }

    #pragma unroll 2
    for (int s = 0; s < 32; ++s) {
      const int se = (s + sw) & 31;            // this wave's staggered K-step
      const int sn = (s + 1 + sw) & 31;        // at s=31 this wraps to sw = next iter's first
      #pragma unroll
      for (int mt = 0; mt < 2; ++mt)
        Ab[(s + 1) & 1][mt] = pA[sn * 1024 + mt * 64];
      uint4 B[2];
      #pragma unroll
      for (int nt = 0; nt < 2; ++nt)
        B[nt] = smem4[(nt * 32 + il) * 64 + ((2 * se + g) ^ il)];   // one ds_read_b128
      #pragma unroll
      for (int mt = 0; mt < 2; ++mt)
        #pragma unroll
        for (int nt = 0; nt < 2; ++nt)
          acc[mt][nt] = mfma32(Ab[s & 1][mt], B[nt], acc[mt][nt]);
    }
    __syncthreads();   // all reads of old a done
    tanhStore();       // overwrite a in place  (Ab[0] already holds next-iter fragments)
    __syncthreads();   // new a visible to all waves
  }

  // ---------- Phase 3: out_proj  y^T = Wout @ a^T (wave w -> channels [w*32, w*32+32)) ----------
  f32x16 o[2];
  #pragma unroll
  for (int nt = 0; nt < 2; ++nt)
    #pragma unroll
    for (int r = 0; r < 16; ++r) o[nt][r] = 0.0f;

  #pragma unroll 2
  for (int s = 0; s < 32; ++s) {
    const int se = (s + sw) & 31;
    const int m = w * 32 + il;                  // output-channel row of Wout
    uint4 A = Wout4[m * 64 + 2 * se + g];
    uint4 B[2];
    #pragma unroll
    for (int nt = 0; nt < 2; ++nt)
      B[nt] = smem4[(nt * 32 + il) * 64 + ((2 * se + g) ^ il)];
    #pragma unroll
    for (int nt = 0; nt < 2; ++nt)
      o[nt] = mfma32(A, B[nt], o[nt]);
  }
  __syncthreads();   // done reading a; reuse LDS as y staging

  // epilogue: +bout, stage f32 rows into LDS (stride-65 uint4 rows)
  uint4* yst4 = smem4;
  #pragma unroll
  for (int p = 0; p < 4; ++p) {
    const int c0 = w * 32 + 8 * p + 4 * g;
    float b0 = boutf[c0 + 0];
    float b1 = boutf[c0 + 1];
    float b2 = boutf[c0 + 2];
    float b3 = boutf[c0 + 3];
    #pragma unroll
    for (int nt = 0; nt < 2; ++nt) {
      const int irow = nt * 32 + il;
      float4 r;
      r.x = o[nt][4 * p + 0] + b0;
      r.y = o[nt][4 * p + 1] + b1;
      r.z = o[nt][4 * p + 2] + b2;
      r.w = o[nt][4 * p + 3] + b3;
      yst4[irow * 65 + (c0 >> 2)] = __builtin_bit_cast(uint4, r);
    }
  }
  __syncthreads();

  // coalesced f32 store: 4096 uint4 per block, 8 passes x 512 threads
  #pragma unroll
  for (int p = 0; p < 8; ++p) {
    int idx = p * 512 + tid;
    int row = idx >> 6;
    int col = idx & 63;
    y4[(blk * 64 + row) * 64 + col] = yst4[row * 65 + col];
  }
}

extern "C" void kernel_launch(void* const* d_in, const int* in_sizes, int n_in,
                              void* d_out, int out_size, void* d_ws, size_t ws_size,
                              hipStream_t stream) {
  const float* x    = (const float*)d_in[0];
  const float* Win  = (const float*)d_in[1];
  const float* bin  = (const float*)d_in[2];
  const float* W    = (const float*)d_in[3];
  const float* brec = (const float*)d_in[4];
  const float* Wout = (const float*)d_in[5];
  const float* bout = (const float*)d_in[6];

  unsigned short* wsu    = (unsigned short*)d_ws;
  unsigned short* WsP    = wsu;            // 262144 bf16 = 512 KB
  unsigned short* WinBf  = wsu + 262144;   // 131072 bf16 = 256 KB
  unsigned short* WoutBf = wsu + 393216;   // 131072 bf16 = 256 KB

  prep<<<1024, 256, 0, stream>>>(W, Win, Wout, WsP, WinBf, WoutBf);
  attractor_kernel<<<1024, 512, 0, stream>>>(x, WinBf, bin, brec, WoutBf, bout,
                                             (const uint4*)WsP, (float*)d_out);
}